// Round 7
// baseline (417.885 us; speedup 1.0000x reference)
//
#include <hip/hip_runtime.h>

// SIGN: N=50000, E=800000, CIN=64, HOPS=3, HID=256, COUT=64
// z PACKED: u32 = (bf16_hi << 16) | bf16_lo, value = hi + lo (~fp32 to 2^-18).
// SPMM: CSR-by-destination, no float atomics. CSR build: XCD-sliced scatter.
// MLP: split-bf16 MFMA. A: double-buffered gload_lds + counted vmcnt(4) + raw
// s_barrier (never drain to 0 mid-loop). B: direct global->VGPR (L2-resident).

#define ZW 256
#define NCH 64

typedef __attribute__((ext_vector_type(8))) __bf16 bf16x8;
typedef __attribute__((ext_vector_type(4))) float f32x4;

__device__ __forceinline__ unsigned f2bf(float f) {
    unsigned x = __float_as_uint(f);
    return (x + 0x7fffu + ((x >> 16) & 1u)) >> 16;   // RNE, finite inputs
}
__device__ __forceinline__ unsigned pack_split(float v) {
    unsigned hb = f2bf(v);
    float hf = __uint_as_float(hb << 16);
    unsigned lb = f2bf(v - hf);
    return (hb << 16) | lb;
}
__device__ __forceinline__ float unpack_f(unsigned u) {
    return __uint_as_float(u & 0xffff0000u) + __uint_as_float(u << 16);
}

// async global->LDS, 16B per lane; LDS dest = uniform base + lane*16 (linear).
__device__ __forceinline__ void gload16(const void* g, void* l) {
    __builtin_amdgcn_global_load_lds(
        (const __attribute__((address_space(1))) unsigned*)g,
        (__attribute__((address_space(3))) unsigned*)l, 16, 0, 0);
}

// ---------------- prologue ----------------

__global__ void init_kernel(const float* __restrict__ x, unsigned* __restrict__ zp,
                            int* __restrict__ deg, int N) {
    int stride = gridDim.x * blockDim.x;
    int total4 = N * 16;
    for (int idx = blockIdx.x * blockDim.x + threadIdx.x; idx < total4; idx += stride) {
        int n = idx >> 4, c4 = idx & 15;
        float4 v = *reinterpret_cast<const float4*>(x + (size_t)n * NCH + c4 * 4);
        uint4 o;
        o.x = pack_split(v.x); o.y = pack_split(v.y);
        o.z = pack_split(v.z); o.w = pack_split(v.w);
        *reinterpret_cast<uint4*>(zp + (size_t)n * ZW + c4 * 4) = o;
    }
    for (int idx = blockIdx.x * blockDim.x + threadIdx.x; idx < N; idx += stride)
        deg[idx] = 0;
}

// XCD-sliced: block-set (blockIdx%8 == s) handles dests in slice s only.
__global__ void degree_kernel(const int* __restrict__ col, int* __restrict__ deg,
                              int E, int N) {
    int slice = blockIdx.x & 7;
    int g = blockIdx.x >> 3;
    int G = gridDim.x >> 3;
    int sliceN = (N + 7) >> 3;
    int lo = slice * sliceN;
    int hi = lo + sliceN; if (hi > N) hi = N;
    int stride = G * blockDim.x;
    for (int e = g * blockDim.x + threadIdx.x; e < E; e += stride) {
        int c = col[e];
        if (c >= lo && c < hi) atomicAdd(&deg[c], 1);
    }
}

__global__ __launch_bounds__(1024) void scan_part_kernel(const int* __restrict__ deg,
                                                         int* __restrict__ off,
                                                         int* __restrict__ bsum, int N) {
    __shared__ int smem[1024];
    int tid = threadIdx.x;
    int i = blockIdx.x * 1024 + tid;
    int v = (i < N) ? deg[i] : 0;
    smem[tid] = v;
    __syncthreads();
    for (int o = 1; o < 1024; o <<= 1) {
        int t = (tid >= o) ? smem[tid - o] : 0;
        __syncthreads();
        smem[tid] += t;
        __syncthreads();
    }
    if (i < N) off[i] = smem[tid] - v;
    if (tid == 1023) bsum[blockIdx.x] = smem[1023];
}

__global__ void scan_tops_kernel(const int* __restrict__ bsum, int* __restrict__ btot, int nb) {
    int lane = threadIdx.x;
    int v = (lane < nb) ? bsum[lane] : 0;
    int incl = v;
    for (int o = 1; o < 64; o <<= 1) {
        int t = __shfl_up(incl, o);
        if (lane >= o) incl += t;
    }
    if (lane < nb) btot[lane] = incl - v;
    if (lane == 63) btot[nb] = incl;
}

__global__ __launch_bounds__(1024) void scan_add_kernel(int* __restrict__ off,
                                                        int* __restrict__ cur,
                                                        const int* __restrict__ btot,
                                                        int N, int nb) {
    int i = blockIdx.x * 1024 + threadIdx.x;
    if (i < N) {
        int o = off[i] + btot[blockIdx.x];
        off[i] = o;
        cur[i] = o;
    }
    if (i == 0) off[N] = btot[nb];
}

// XCD-sliced scatter: slice-set s scatters only edges with col in slice s.
__global__ void scatter_kernel(const int* __restrict__ row, const int* __restrict__ col,
                               const int* __restrict__ deg, int* __restrict__ cursor,
                               int2* __restrict__ meta, int E, int N) {
    int slice = blockIdx.x & 7;
    int g = blockIdx.x >> 3;
    int G = gridDim.x >> 3;
    int sliceN = (N + 7) >> 3;
    int lo = slice * sliceN;
    int hi = lo + sliceN; if (hi > N) hi = N;
    int stride = G * blockDim.x;
    for (int e = g * blockDim.x + threadIdx.x; e < E; e += stride) {
        int c = col[e];
        if (c >= lo && c < hi) {
            int r = row[e];
            int dc = deg[c];
            int dr = deg[r];
            float v = 0.0f;
            if (dc > 0 && dr > 0) v = rsqrtf((float)dc * (float)dr);
            int pos = atomicAdd(&cursor[c], 1);
            meta[pos] = make_int2(r, __float_as_int(v));
        }
    }
}

// One wave per destination node; lane = channel. 4-wide unroll for gather ILP.
__global__ void spmm_csr_kernel(const int* __restrict__ offsets, const int2* __restrict__ meta,
                                const unsigned* __restrict__ zin, unsigned* __restrict__ zout,
                                int N) {
    int lane = threadIdx.x & 63;
    int wave = (blockIdx.x * blockDim.x + threadIdx.x) >> 6;
    if (wave >= N) return;
    int start = offsets[wave];
    int end   = offsets[wave + 1];
    float acc = 0.0f;
    int j = start;
    for (; j + 4 <= end; j += 4) {
        int2 m0 = meta[j];
        int2 m1 = meta[j + 1];
        int2 m2 = meta[j + 2];
        int2 m3 = meta[j + 3];
        float h0 = unpack_f(zin[(size_t)m0.x * ZW + lane]);
        float h1 = unpack_f(zin[(size_t)m1.x * ZW + lane]);
        float h2 = unpack_f(zin[(size_t)m2.x * ZW + lane]);
        float h3 = unpack_f(zin[(size_t)m3.x * ZW + lane]);
        acc = fmaf(__int_as_float(m0.y), h0, acc);
        acc = fmaf(__int_as_float(m1.y), h1, acc);
        acc = fmaf(__int_as_float(m2.y), h2, acc);
        acc = fmaf(__int_as_float(m3.y), h3, acc);
    }
    for (; j + 2 <= end; j += 2) {
        int2 m0 = meta[j];
        int2 m1 = meta[j + 1];
        float h0 = unpack_f(zin[(size_t)m0.x * ZW + lane]);
        float h1 = unpack_f(zin[(size_t)m1.x * ZW + lane]);
        acc = fmaf(__int_as_float(m0.y), h0, acc);
        acc = fmaf(__int_as_float(m1.y), h1, acc);
    }
    if (j < end) {
        int2 m0 = meta[j];
        acc = fmaf(__int_as_float(m0.y), unpack_f(zin[(size_t)m0.x * ZW + lane]), acc);
    }
    zout[(size_t)wave * ZW + lane] = pack_split(acc);
}

// Split + transpose weights: W[k][n] fp32 -> Wh/Wl[n][k] bf16 (ushort bits).
__global__ void prep_w_kernel(const float* __restrict__ W0, const float* __restrict__ W1,
                              const float* __restrict__ W2, unsigned short* __restrict__ ws) {
    int idx = blockIdx.x * blockDim.x + threadIdx.x;
    if (idx >= 65536) return;
    int n = idx >> 8, k = idx & 255;
    unsigned p0 = pack_split(W0[(size_t)k * 256 + n]);
    ws[idx]          = (unsigned short)(p0 >> 16);
    ws[65536 + idx]  = (unsigned short)(p0 & 0xffff);
    unsigned p1 = pack_split(W1[(size_t)k * 256 + n]);
    ws[131072 + idx] = (unsigned short)(p1 >> 16);
    ws[196608 + idx] = (unsigned short)(p1 & 0xffff);
    if (idx < 16384) {
        int n2 = idx >> 8, k2 = idx & 255;       // n2 in [0,64)
        unsigned p2 = pack_split(W2[(size_t)k2 * 64 + n2]);
        ws[262144 + idx] = (unsigned short)(p2 >> 16);
        ws[278528 + idx] = (unsigned short)(p2 & 0xffff);
    }
}

// ---------- GEMM 1/2: Cp[M,256] = relu(Ap@W + b), packed in/out ----------
// BM=128, BN=128, BK=32; 4 waves (2x2), wave tile 64x64.
// A: gload_lds dbuf (32 KB), counted vmcnt(4), raw barriers. B: global->VGPR.
__global__ __launch_bounds__(256, 3) void gemm256_kernel(
        const unsigned* __restrict__ Ap, const unsigned short* __restrict__ Wh,
        const unsigned short* __restrict__ Wl, const float* __restrict__ bias,
        unsigned* __restrict__ Cp, int M) {
    __shared__ unsigned Apl[2 * 128 * 32];          // 32 KB

    int tid = threadIdx.x;
    int lane = tid & 63;
    int wid = tid >> 6;
    int wr = wid >> 1, wc = wid & 1;
    int bm = blockIdx.x * 128;
    int bn = blockIdx.y * 128;
    int l15 = lane & 15, kg = lane >> 4;

    f32x4 acc[4][4] = {};

    auto STAGE = [&](int buf, int k0) {
        unsigned* Ab = Apl + buf * (128 * 32);
#pragma unroll
        for (int i = 0; i < 4; ++i) {
            int s = (wid * 4 + i) * 64 + lane;       // chunk-slot 0..1023
            int r = s >> 3, cp = s & 7;
            int cl = cp ^ (r & 7);
            int grow = bm + r; if (grow >= M) grow = M - 1;
            gload16(Ap + (size_t)grow * 256 + k0 + cl * 4, Ab + (wid * 4 + i) * 256);
        }
    };

    auto COMPUTE = [&](int buf, int k0) {
        const unsigned* Ab = Apl + buf * (128 * 32);
        bf16x8 bh[4], bl[4];
#pragma unroll
        for (int n4 = 0; n4 < 4; ++n4) {
            int nn = wc * 64 + n4 * 16 + l15;
            size_t go = (size_t)(bn + nn) * 256 + k0 + kg * 8;
            bh[n4] = *reinterpret_cast<const bf16x8*>(Wh + go);
            bl[n4] = *reinterpret_cast<const bf16x8*>(Wl + go);
        }
#pragma unroll
        for (int m = 0; m < 4; ++m) {
            int r = wr * 64 + m * 16 + l15;
            int c0 = (2 * kg) ^ (r & 7);
            int c1 = (2 * kg + 1) ^ (r & 7);
            uint4 q0 = *reinterpret_cast<const uint4*>(&Ab[r * 32 + c0 * 4]);
            uint4 q1 = *reinterpret_cast<const uint4*>(&Ab[r * 32 + c1 * 4]);
            union { bf16x8 v; unsigned short s[8]; } ah, al;
            ah.s[0] = (unsigned short)(q0.x >> 16); al.s[0] = (unsigned short)q0.x;
            ah.s[1] = (unsigned short)(q0.y >> 16); al.s[1] = (unsigned short)q0.y;
            ah.s[2] = (unsigned short)(q0.z >> 16); al.s[2] = (unsigned short)q0.z;
            ah.s[3] = (unsigned short)(q0.w >> 16); al.s[3] = (unsigned short)q0.w;
            ah.s[4] = (unsigned short)(q1.x >> 16); al.s[4] = (unsigned short)q1.x;
            ah.s[5] = (unsigned short)(q1.y >> 16); al.s[5] = (unsigned short)q1.y;
            ah.s[6] = (unsigned short)(q1.z >> 16); al.s[6] = (unsigned short)q1.z;
            ah.s[7] = (unsigned short)(q1.w >> 16); al.s[7] = (unsigned short)q1.w;
#pragma unroll
            for (int n4 = 0; n4 < 4; ++n4) {
                acc[m][n4] = __builtin_amdgcn_mfma_f32_16x16x32_bf16(ah.v, bh[n4], acc[m][n4], 0, 0, 0);
                acc[m][n4] = __builtin_amdgcn_mfma_f32_16x16x32_bf16(ah.v, bl[n4], acc[m][n4], 0, 0, 0);
                acc[m][n4] = __builtin_amdgcn_mfma_f32_16x16x32_bf16(al.v, bh[n4], acc[m][n4], 0, 0, 0);
            }
        }
    };

    STAGE(0, 0);
#pragma unroll
    for (int t = 0; t < 8; ++t) {
        if (t < 7) {
            STAGE((t + 1) & 1, (t + 1) * 32);
            asm volatile("s_waitcnt vmcnt(4)" ::: "memory");   // cur's 4 A-loads done; nxt's stay in flight
        } else {
            asm volatile("s_waitcnt vmcnt(0)" ::: "memory");
        }
        __builtin_amdgcn_s_barrier();                          // all waves' cur-tile staged
        COMPUTE(t & 1, t * 32);
        __builtin_amdgcn_s_barrier();                          // all waves done reading before overwrite
        __builtin_amdgcn_sched_barrier(0);                     // pin: no hoist of next STAGE above
    }

    // epilogue: C row = kg*4 + reg, col = l15 within each 16x16 frag [m89]
#pragma unroll
    for (int n4 = 0; n4 < 4; ++n4) {
        int col = bn + wc * 64 + n4 * 16 + l15;
        float bv = bias[col];
#pragma unroll
        for (int m = 0; m < 4; ++m) {
#pragma unroll
            for (int rr = 0; rr < 4; ++rr) {
                int row = bm + wr * 64 + m * 16 + kg * 4 + rr;
                if (row < M) {
                    float v = fmaxf(acc[m][n4][rr] + bv, 0.0f);
                    Cp[(size_t)row * 256 + col] = pack_split(v);
                }
            }
        }
    }
}

// ---------- GEMM 3: out[M,64] = Ap@W2 + b2 (fp32 out) ----------
// BM=128 (4 waves stacked, wave tile 32x64), BN=64; same pipeline.
__global__ __launch_bounds__(256, 3) void gemm64_kernel(
        const unsigned* __restrict__ Ap, const unsigned short* __restrict__ Wh,
        const unsigned short* __restrict__ Wl, const float* __restrict__ bias,
        float* __restrict__ out, int M) {
    __shared__ unsigned Apl[2 * 128 * 32];          // 32 KB

    int tid = threadIdx.x;
    int lane = tid & 63;
    int wid = tid >> 6;
    int bm = blockIdx.x * 128;
    int l15 = lane & 15, kg = lane >> 4;

    f32x4 acc[2][4] = {};

    auto STAGE = [&](int buf, int k0) {
        unsigned* Ab = Apl + buf * (128 * 32);
#pragma unroll
        for (int i = 0; i < 4; ++i) {
            int s = (wid * 4 + i) * 64 + lane;
            int r = s >> 3, cp = s & 7;
            int cl = cp ^ (r & 7);
            int grow = bm + r; if (grow >= M) grow = M - 1;
            gload16(Ap + (size_t)grow * 256 + k0 + cl * 4, Ab + (wid * 4 + i) * 256);
        }
    };

    auto COMPUTE = [&](int buf, int k0) {
        const unsigned* Ab = Apl + buf * (128 * 32);
        bf16x8 bh[4], bl[4];
#pragma unroll
        for (int n4 = 0; n4 < 4; ++n4) {
            int nn = n4 * 16 + l15;
            size_t go = (size_t)nn * 256 + k0 + kg * 8;
            bh[n4] = *reinterpret_cast<const bf16x8*>(Wh + go);
            bl[n4] = *reinterpret_cast<const bf16x8*>(Wl + go);
        }
#pragma unroll
        for (int m = 0; m < 2; ++m) {
            int r = wid * 32 + m * 16 + l15;
            int c0 = (2 * kg) ^ (r & 7);
            int c1 = (2 * kg + 1) ^ (r & 7);
            uint4 q0 = *reinterpret_cast<const uint4*>(&Ab[r * 32 + c0 * 4]);
            uint4 q1 = *reinterpret_cast<const uint4*>(&Ab[r * 32 + c1 * 4]);
            union { bf16x8 v; unsigned short s[8]; } ah, al;
            ah.s[0] = (unsigned short)(q0.x >> 16); al.s[0] = (unsigned short)q0.x;
            ah.s[1] = (unsigned short)(q0.y >> 16); al.s[1] = (unsigned short)q0.y;
            ah.s[2] = (unsigned short)(q0.z >> 16); al.s[2] = (unsigned short)q0.z;
            ah.s[3] = (unsigned short)(q0.w >> 16); al.s[3] = (unsigned short)q0.w;
            ah.s[4] = (unsigned short)(q1.x >> 16); al.s[4] = (unsigned short)q1.x;
            ah.s[5] = (unsigned short)(q1.y >> 16); al.s[5] = (unsigned short)q1.y;
            ah.s[6] = (unsigned short)(q1.z >> 16); al.s[6] = (unsigned short)q1.z;
            ah.s[7] = (unsigned short)(q1.w >> 16); al.s[7] = (unsigned short)q1.w;
#pragma unroll
            for (int n4 = 0; n4 < 4; ++n4) {
                acc[m][n4] = __builtin_amdgcn_mfma_f32_16x16x32_bf16(ah.v, bh[n4], acc[m][n4], 0, 0, 0);
                acc[m][n4] = __builtin_amdgcn_mfma_f32_16x16x32_bf16(ah.v, bl[n4], acc[m][n4], 0, 0, 0);
                acc[m][n4] = __builtin_amdgcn_mfma_f32_16x16x32_bf16(al.v, bh[n4], acc[m][n4], 0, 0, 0);
            }
        }
    };

    STAGE(0, 0);
#pragma unroll
    for (int t = 0; t < 8; ++t) {
        if (t < 7) {
            STAGE((t + 1) & 1, (t + 1) * 32);
            asm volatile("s_waitcnt vmcnt(4)" ::: "memory");
        } else {
            asm volatile("s_waitcnt vmcnt(0)" ::: "memory");
        }
        __builtin_amdgcn_s_barrier();
        COMPUTE(t & 1, t * 32);
        __builtin_amdgcn_s_barrier();
        __builtin_amdgcn_sched_barrier(0);
    }

#pragma unroll
    for (int n4 = 0; n4 < 4; ++n4) {
        int col = n4 * 16 + l15;
        float bv = bias[col];
#pragma unroll
        for (int m = 0; m < 2; ++m) {
#pragma unroll
            for (int rr = 0; rr < 4; ++rr) {
                int row = bm + wid * 32 + m * 16 + kg * 4 + rr;
                if (row < M) out[(size_t)row * 64 + col] = acc[m][n4][rr] + bv;
            }
        }
    }
}

extern "C" void kernel_launch(void* const* d_in, const int* in_sizes, int n_in,
                              void* d_out, int out_size, void* d_ws, size_t ws_size,
                              hipStream_t stream) {
    const float* x  = (const float*)d_in[0];
    const int* ei   = (const int*)d_in[1];
    const float* W0 = (const float*)d_in[2];
    const float* b0 = (const float*)d_in[3];
    const float* W1 = (const float*)d_in[4];
    const float* b1 = (const float*)d_in[5];
    const float* W2 = (const float*)d_in[6];
    const float* b2 = (const float*)d_in[7];
    float* out = (float*)d_out;

    const int N = in_sizes[0] / NCH;      // 50000
    const int E = in_sizes[1] / 2;        // 800000
    const int* row = ei;
    const int* col = ei + E;

    // workspace
    unsigned* zp = (unsigned*)d_ws;                       // N*256 u32
    unsigned* hp = zp + (size_t)N * ZW;                   // N*256 u32 (meta overlay)
    unsigned short* wsp = (unsigned short*)(hp + (size_t)N * ZW);  // 294912 ushorts
    int* deg  = (int*)(wsp + 294912);                     // N
    int* off  = deg + N;                                  // N+1
    int* cur  = off + N + 1;                              // N
    int* bsum = cur + N;                                  // 64
    int* btot = bsum + 64;                                // 80
    int2* meta = (int2*)hp;                               // overlays hp (disjoint lifetime)

    const int TB = 256;
    const int NB = (N + 1023) / 1024;

    prep_w_kernel<<<256, TB, 0, stream>>>(W0, W1, W2, wsp);
    init_kernel<<<2048, TB, 0, stream>>>(x, zp, deg, N);
    degree_kernel<<<1024, TB, 0, stream>>>(col, deg, E, N);
    scan_part_kernel<<<NB, 1024, 0, stream>>>(deg, off, bsum, N);
    scan_tops_kernel<<<1, 64, 0, stream>>>(bsum, btot, NB);
    scan_add_kernel<<<NB, 1024, 0, stream>>>(off, cur, btot, N, NB);
    scatter_kernel<<<1024, TB, 0, stream>>>(row, col, deg, cur, meta, E, N);

    int spmm_blocks = (N * 64 + TB - 1) / TB;
    for (int hop = 1; hop <= 3; ++hop) {
        const unsigned* zin = zp + (hop - 1) * NCH;
        unsigned* zout      = zp + hop * NCH;
        spmm_csr_kernel<<<spmm_blocks, TB, 0, stream>>>(off, meta, zin, zout, N);
    }

    int gblocks = (N + 127) / 128;                        // 391
    dim3 g256(gblocks, 2);
    gemm256_kernel<<<g256, TB, 0, stream>>>(zp, wsp,          wsp + 65536,  b0, hp, N);
    gemm256_kernel<<<g256, TB, 0, stream>>>(hp, wsp + 131072, wsp + 196608, b1, zp, N);
    gemm64_kernel<<<gblocks, TB, 0, stream>>>(zp, wsp + 262144, wsp + 278528, b2, out, N);
}

// Round 10
// 350.284 us; speedup vs baseline: 1.1930x; 1.1930x over previous
//
#include <hip/hip_runtime.h>

// SIGN: N=50000, E=800000, CIN=64, HOPS=3, HID=256, COUT=64
// z PACKED: u32 = (bf16_hi << 16) | bf16_lo, value = hi + lo (~fp32 to 2^-18).
// SPMM: CSR-by-destination, no float atomics. CSR build: XCD-sliced scatter.
// MLP: ONE fused kernel (3 layers). z read once, out written once; h0/h1 live
// in a shared 64KB LDS buffer (XOR-swizzled). Split-bf16 MFMA throughout.

#define ZW 256
#define NCH 64

typedef __attribute__((ext_vector_type(8))) __bf16 bf16x8;
typedef __attribute__((ext_vector_type(4))) float f32x4;

__device__ __forceinline__ unsigned f2bf(float f) {
    unsigned x = __float_as_uint(f);
    return (x + 0x7fffu + ((x >> 16) & 1u)) >> 16;   // RNE, finite inputs
}
__device__ __forceinline__ unsigned pack_split(float v) {
    unsigned hb = f2bf(v);
    float hf = __uint_as_float(hb << 16);
    unsigned lb = f2bf(v - hf);
    return (hb << 16) | lb;
}
__device__ __forceinline__ float unpack_f(unsigned u) {
    return __uint_as_float(u & 0xffff0000u) + __uint_as_float(u << 16);
}

// async global->LDS, 16B per lane; LDS dest = uniform base + lane*16 (linear).
__device__ __forceinline__ void gload16(const void* g, void* l) {
    __builtin_amdgcn_global_load_lds(
        (const __attribute__((address_space(1))) unsigned*)g,
        (__attribute__((address_space(3))) unsigned*)l, 16, 0, 0);
}

// unpack 8 packed u32 (two uint4) -> hi/lo bf16x8
union bfu { bf16x8 v; unsigned short s[8]; };
__device__ __forceinline__ void unpack8(uint4 q0, uint4 q1, bfu& ah, bfu& al) {
    ah.s[0] = (unsigned short)(q0.x >> 16); al.s[0] = (unsigned short)q0.x;
    ah.s[1] = (unsigned short)(q0.y >> 16); al.s[1] = (unsigned short)q0.y;
    ah.s[2] = (unsigned short)(q0.z >> 16); al.s[2] = (unsigned short)q0.z;
    ah.s[3] = (unsigned short)(q0.w >> 16); al.s[3] = (unsigned short)q0.w;
    ah.s[4] = (unsigned short)(q1.x >> 16); al.s[4] = (unsigned short)q1.x;
    ah.s[5] = (unsigned short)(q1.y >> 16); al.s[5] = (unsigned short)q1.y;
    ah.s[6] = (unsigned short)(q1.z >> 16); al.s[6] = (unsigned short)q1.z;
    ah.s[7] = (unsigned short)(q1.w >> 16); al.s[7] = (unsigned short)q1.w;
}

// ---------------- prologue ----------------

__global__ void init_kernel(const float* __restrict__ x, unsigned* __restrict__ zp,
                            int* __restrict__ deg, int N) {
    int stride = gridDim.x * blockDim.x;
    int total4 = N * 16;
    for (int idx = blockIdx.x * blockDim.x + threadIdx.x; idx < total4; idx += stride) {
        int n = idx >> 4, c4 = idx & 15;
        float4 v = *reinterpret_cast<const float4*>(x + (size_t)n * NCH + c4 * 4);
        uint4 o;
        o.x = pack_split(v.x); o.y = pack_split(v.y);
        o.z = pack_split(v.z); o.w = pack_split(v.w);
        *reinterpret_cast<uint4*>(zp + (size_t)n * ZW + c4 * 4) = o;
    }
    for (int idx = blockIdx.x * blockDim.x + threadIdx.x; idx < N; idx += stride)
        deg[idx] = 0;
}

// XCD-sliced: block-set (blockIdx%8 == s) handles dests in slice s only.
__global__ void degree_kernel(const int* __restrict__ col, int* __restrict__ deg,
                              int E, int N) {
    int slice = blockIdx.x & 7;
    int g = blockIdx.x >> 3;
    int G = gridDim.x >> 3;
    int sliceN = (N + 7) >> 3;
    int lo = slice * sliceN;
    int hi = lo + sliceN; if (hi > N) hi = N;
    int stride = G * blockDim.x;
    for (int e = g * blockDim.x + threadIdx.x; e < E; e += stride) {
        int c = col[e];
        if (c >= lo && c < hi) atomicAdd(&deg[c], 1);
    }
}

__global__ __launch_bounds__(1024) void scan_part_kernel(const int* __restrict__ deg,
                                                         int* __restrict__ off,
                                                         int* __restrict__ bsum, int N) {
    __shared__ int smem[1024];
    int tid = threadIdx.x;
    int i = blockIdx.x * 1024 + tid;
    int v = (i < N) ? deg[i] : 0;
    smem[tid] = v;
    __syncthreads();
    for (int o = 1; o < 1024; o <<= 1) {
        int t = (tid >= o) ? smem[tid - o] : 0;
        __syncthreads();
        smem[tid] += t;
        __syncthreads();
    }
    if (i < N) off[i] = smem[tid] - v;
    if (tid == 1023) bsum[blockIdx.x] = smem[1023];
}

__global__ void scan_tops_kernel(const int* __restrict__ bsum, int* __restrict__ btot, int nb) {
    int lane = threadIdx.x;
    int v = (lane < nb) ? bsum[lane] : 0;
    int incl = v;
    for (int o = 1; o < 64; o <<= 1) {
        int t = __shfl_up(incl, o);
        if (lane >= o) incl += t;
    }
    if (lane < nb) btot[lane] = incl - v;
    if (lane == 63) btot[nb] = incl;
}

__global__ __launch_bounds__(1024) void scan_add_kernel(int* __restrict__ off,
                                                        int* __restrict__ cur,
                                                        const int* __restrict__ btot,
                                                        int N, int nb) {
    int i = blockIdx.x * 1024 + threadIdx.x;
    if (i < N) {
        int o = off[i] + btot[blockIdx.x];
        off[i] = o;
        cur[i] = o;
    }
    if (i == 0) off[N] = btot[nb];
}

// XCD-sliced scatter: slice-set s scatters only edges with col in slice s.
__global__ void scatter_kernel(const int* __restrict__ row, const int* __restrict__ col,
                               const int* __restrict__ deg, int* __restrict__ cursor,
                               int2* __restrict__ meta, int E, int N) {
    int slice = blockIdx.x & 7;
    int g = blockIdx.x >> 3;
    int G = gridDim.x >> 3;
    int sliceN = (N + 7) >> 3;
    int lo = slice * sliceN;
    int hi = lo + sliceN; if (hi > N) hi = N;
    int stride = G * blockDim.x;
    for (int e = g * blockDim.x + threadIdx.x; e < E; e += stride) {
        int c = col[e];
        if (c >= lo && c < hi) {
            int r = row[e];
            int dc = deg[c];
            int dr = deg[r];
            float v = 0.0f;
            if (dc > 0 && dr > 0) v = rsqrtf((float)dc * (float)dr);
            int pos = atomicAdd(&cursor[c], 1);
            meta[pos] = make_int2(r, __float_as_int(v));
        }
    }
}

// One wave per destination node; lane = channel. 4-wide unroll for gather ILP.
__global__ void spmm_csr_kernel(const int* __restrict__ offsets, const int2* __restrict__ meta,
                                const unsigned* __restrict__ zin, unsigned* __restrict__ zout,
                                int N) {
    int lane = threadIdx.x & 63;
    int wave = (blockIdx.x * blockDim.x + threadIdx.x) >> 6;
    if (wave >= N) return;
    int start = offsets[wave];
    int end   = offsets[wave + 1];
    float acc = 0.0f;
    int j = start;
    for (; j + 4 <= end; j += 4) {
        int2 m0 = meta[j];
        int2 m1 = meta[j + 1];
        int2 m2 = meta[j + 2];
        int2 m3 = meta[j + 3];
        float h0 = unpack_f(zin[(size_t)m0.x * ZW + lane]);
        float h1 = unpack_f(zin[(size_t)m1.x * ZW + lane]);
        float h2 = unpack_f(zin[(size_t)m2.x * ZW + lane]);
        float h3 = unpack_f(zin[(size_t)m3.x * ZW + lane]);
        acc = fmaf(__int_as_float(m0.y), h0, acc);
        acc = fmaf(__int_as_float(m1.y), h1, acc);
        acc = fmaf(__int_as_float(m2.y), h2, acc);
        acc = fmaf(__int_as_float(m3.y), h3, acc);
    }
    for (; j + 2 <= end; j += 2) {
        int2 m0 = meta[j];
        int2 m1 = meta[j + 1];
        float h0 = unpack_f(zin[(size_t)m0.x * ZW + lane]);
        float h1 = unpack_f(zin[(size_t)m1.x * ZW + lane]);
        acc = fmaf(__int_as_float(m0.y), h0, acc);
        acc = fmaf(__int_as_float(m1.y), h1, acc);
    }
    if (j < end) {
        int2 m0 = meta[j];
        acc = fmaf(__int_as_float(m0.y), unpack_f(zin[(size_t)m0.x * ZW + lane]), acc);
    }
    zout[(size_t)wave * ZW + lane] = pack_split(acc);
}

// Split + transpose weights: W[k][n] fp32 -> Wh/Wl[n][k] bf16 (ushort bits).
__global__ void prep_w_kernel(const float* __restrict__ W0, const float* __restrict__ W1,
                              const float* __restrict__ W2, unsigned short* __restrict__ ws) {
    int idx = blockIdx.x * blockDim.x + threadIdx.x;
    if (idx >= 65536) return;
    int n = idx >> 8, k = idx & 255;
    unsigned p0 = pack_split(W0[(size_t)k * 256 + n]);
    ws[idx]          = (unsigned short)(p0 >> 16);
    ws[65536 + idx]  = (unsigned short)(p0 & 0xffff);
    unsigned p1 = pack_split(W1[(size_t)k * 256 + n]);
    ws[131072 + idx] = (unsigned short)(p1 >> 16);
    ws[196608 + idx] = (unsigned short)(p1 & 0xffff);
    if (idx < 16384) {
        int n2 = idx >> 8, k2 = idx & 255;       // n2 in [0,64)
        unsigned p2 = pack_split(W2[(size_t)k2 * 64 + n2]);
        ws[262144 + idx] = (unsigned short)(p2 >> 16);
        ws[278528 + idx] = (unsigned short)(p2 & 0xffff);
    }
}

// ---------- Fused MLP: out[M,64] = relu(relu(z@W0+b0)@W1+b1)@W2 + b2 ----------
// Block = 64 rows, 4 waves. Phase0: z staged (gload_lds dbuf) -> h0 -> LDS H.
// Phase1: H(LDS) @ W1 -> H. Phase2: H(LDS) @ W2 -> out. W* read from L2.
// H: 64x256 packed u32, 16B-chunk XOR swizzle j^= (r&7) (T2, row-strided reads free).
__global__ __launch_bounds__(256, 2) void mlp_fused_kernel(
        const unsigned* __restrict__ Ap, const unsigned short* __restrict__ wsp,
        const float* __restrict__ b0, const float* __restrict__ b1,
        const float* __restrict__ b2, float* __restrict__ out, int M) {
    __shared__ unsigned Ast[2 * 64 * 32];   // 16 KB (A K-chunk double buffer)
    __shared__ unsigned Hs[64 * 256];       // 64 KB (h0/h1, packed, swizzled)

    const unsigned short* W0h = wsp;
    const unsigned short* W0l = wsp + 65536;
    const unsigned short* W1h = wsp + 131072;
    const unsigned short* W1l = wsp + 196608;
    const unsigned short* W2h = wsp + 262144;
    const unsigned short* W2l = wsp + 278528;

    int tid = threadIdx.x;
    int lane = tid & 63;
    int wid = tid >> 6;
    int bm = blockIdx.x * 64;
    int l15 = lane & 15, kg = lane >> 4;

    f32x4 acc[4][4] = {};

    auto STAGE = [&](int buf, int k0) {
        unsigned* Ab = Ast + buf * 2048;
#pragma unroll
        for (int q = 0; q < 2; ++q) {
            int s = (wid * 2 + q) * 64 + lane;     // chunk-slot 0..511
            int r = s >> 3, cp = s & 7;
            int cl = cp ^ (r & 7);
            int grow = bm + r; if (grow >= M) grow = M - 1;
            gload16(Ap + (size_t)grow * 256 + k0 + cl * 4, Ab + (wid * 2 + q) * 256);
        }
    };

    // ---- phase 0: h0 = relu(z @ W0 + b0), wave wid owns cols wid*64.. ----
    auto COMPUTE0 = [&](int buf, int k0) {
        const unsigned* Ab = Ast + buf * 2048;
        bf16x8 bh[4], bl[4];
#pragma unroll
        for (int n4 = 0; n4 < 4; ++n4) {
            int nn = wid * 64 + n4 * 16 + l15;
            size_t go = (size_t)nn * 256 + k0 + kg * 8;
            bh[n4] = *reinterpret_cast<const bf16x8*>(W0h + go);
            bl[n4] = *reinterpret_cast<const bf16x8*>(W0l + go);
        }
#pragma unroll
        for (int m = 0; m < 4; ++m) {
            int r = m * 16 + l15;
            int c0 = (2 * kg) ^ (r & 7);
            int c1 = (2 * kg + 1) ^ (r & 7);
            uint4 q0 = *reinterpret_cast<const uint4*>(&Ab[r * 32 + c0 * 4]);
            uint4 q1 = *reinterpret_cast<const uint4*>(&Ab[r * 32 + c1 * 4]);
            bfu ah, al;
            unpack8(q0, q1, ah, al);
#pragma unroll
            for (int n4 = 0; n4 < 4; ++n4) {
                acc[m][n4] = __builtin_amdgcn_mfma_f32_16x16x32_bf16(ah.v, bh[n4], acc[m][n4], 0, 0, 0);
                acc[m][n4] = __builtin_amdgcn_mfma_f32_16x16x32_bf16(ah.v, bl[n4], acc[m][n4], 0, 0, 0);
                acc[m][n4] = __builtin_amdgcn_mfma_f32_16x16x32_bf16(al.v, bh[n4], acc[m][n4], 0, 0, 0);
            }
        }
    };

    STAGE(0, 0);
#pragma unroll
    for (int t = 0; t < 8; ++t) {
        if (t < 7) {
            STAGE((t + 1) & 1, (t + 1) * 32);
            asm volatile("s_waitcnt vmcnt(2)" ::: "memory");   // cur's 2 A-loads done
        } else {
            asm volatile("s_waitcnt vmcnt(0)" ::: "memory");
        }
        __builtin_amdgcn_s_barrier();
        COMPUTE0(t & 1, t * 32);
        __builtin_amdgcn_s_barrier();
        __builtin_amdgcn_sched_barrier(0);
    }

    // write h0 -> Hs (swizzled). C frag: row = m*16 + kg*4 + rr, col = base + l15.
    auto hwrite = [&](int r, int c, float v) {
        int j = (c >> 2) ^ (r & 7);
        Hs[r * 256 + j * 4 + (c & 3)] = pack_split(v);
    };
#pragma unroll
    for (int n4 = 0; n4 < 4; ++n4) {
        int c = wid * 64 + n4 * 16 + l15;
        float bv = b0[c];
#pragma unroll
        for (int m = 0; m < 4; ++m)
#pragma unroll
            for (int rr = 0; rr < 4; ++rr) {
                int r = m * 16 + kg * 4 + rr;
                hwrite(r, c, fmaxf(acc[m][n4][rr] + bv, 0.0f));
                acc[m][n4][rr] = 0.0f;                 // reset for phase 1
            }
    }
    __syncthreads();

    // ---- phase 1: h1 = relu(H @ W1 + b1); A from LDS, no barriers in K-loop ----
    for (int k0 = 0; k0 < 256; k0 += 32) {
        bf16x8 bh[4], bl[4];
#pragma unroll
        for (int n4 = 0; n4 < 4; ++n4) {
            int nn = wid * 64 + n4 * 16 + l15;
            size_t go = (size_t)nn * 256 + k0 + kg * 8;
            bh[n4] = *reinterpret_cast<const bf16x8*>(W1h + go);
            bl[n4] = *reinterpret_cast<const bf16x8*>(W1l + go);
        }
#pragma unroll
        for (int m = 0; m < 4; ++m) {
            int r = m * 16 + l15;
            int jb = (k0 >> 2) + 2 * kg;
            uint4 q0 = *reinterpret_cast<const uint4*>(&Hs[r * 256 + (jb ^ (r & 7)) * 4]);
            uint4 q1 = *reinterpret_cast<const uint4*>(&Hs[r * 256 + ((jb + 1) ^ (r & 7)) * 4]);
            bfu ah, al;
            unpack8(q0, q1, ah, al);
#pragma unroll
            for (int n4 = 0; n4 < 4; ++n4) {
                acc[m][n4] = __builtin_amdgcn_mfma_f32_16x16x32_bf16(ah.v, bh[n4], acc[m][n4], 0, 0, 0);
                acc[m][n4] = __builtin_amdgcn_mfma_f32_16x16x32_bf16(ah.v, bl[n4], acc[m][n4], 0, 0, 0);
                acc[m][n4] = __builtin_amdgcn_mfma_f32_16x16x32_bf16(al.v, bh[n4], acc[m][n4], 0, 0, 0);
            }
        }
    }
    __syncthreads();   // all H reads done before overwrite
#pragma unroll
    for (int n4 = 0; n4 < 4; ++n4) {
        int c = wid * 64 + n4 * 16 + l15;
        float bv = b1[c];
#pragma unroll
        for (int m = 0; m < 4; ++m)
#pragma unroll
            for (int rr = 0; rr < 4; ++rr) {
                int r = m * 16 + kg * 4 + rr;
                hwrite(r, c, fmaxf(acc[m][n4][rr] + bv, 0.0f));
            }
    }
    __syncthreads();

    // ---- phase 2: out = H @ W2 + b2; wave wid owns cols wid*16.. ----
    f32x4 acc2[4] = {};
    for (int k0 = 0; k0 < 256; k0 += 32) {
        int nn = wid * 16 + l15;
        size_t go = (size_t)nn * 256 + k0 + kg * 8;
        bf16x8 bh2 = *reinterpret_cast<const bf16x8*>(W2h + go);
        bf16x8 bl2 = *reinterpret_cast<const bf16x8*>(W2l + go);
#pragma unroll
        for (int m = 0; m < 4; ++m) {
            int r = m * 16 + l15;
            int jb = (k0 >> 2) + 2 * kg;
            uint4 q0 = *reinterpret_cast<const uint4*>(&Hs[r * 256 + (jb ^ (r & 7)) * 4]);
            uint4 q1 = *reinterpret_cast<const uint4*>(&Hs[r * 256 + ((jb + 1) ^ (r & 7)) * 4]);
            bfu ah, al;
            unpack8(q0, q1, ah, al);
            acc2[m] = __builtin_amdgcn_mfma_f32_16x16x32_bf16(ah.v, bh2, acc2[m], 0, 0, 0);
            acc2[m] = __builtin_amdgcn_mfma_f32_16x16x32_bf16(ah.v, bl2, acc2[m], 0, 0, 0);
            acc2[m] = __builtin_amdgcn_mfma_f32_16x16x32_bf16(al.v, bh2, acc2[m], 0, 0, 0);
        }
    }
    {
        int c = wid * 16 + l15;
        float bv = b2[c];
#pragma unroll
        for (int m = 0; m < 4; ++m)
#pragma unroll
            for (int rr = 0; rr < 4; ++rr) {
                int row = bm + m * 16 + kg * 4 + rr;
                if (row < M) out[(size_t)row * 64 + c] = acc2[m][rr] + bv;
            }
    }
}

extern "C" void kernel_launch(void* const* d_in, const int* in_sizes, int n_in,
                              void* d_out, int out_size, void* d_ws, size_t ws_size,
                              hipStream_t stream) {
    const float* x  = (const float*)d_in[0];
    const int* ei   = (const int*)d_in[1];
    const float* W0 = (const float*)d_in[2];
    const float* b0 = (const float*)d_in[3];
    const float* W1 = (const float*)d_in[4];
    const float* b1 = (const float*)d_in[5];
    const float* W2 = (const float*)d_in[6];
    const float* b2 = (const float*)d_in[7];
    float* out = (float*)d_out;

    const int N = in_sizes[0] / NCH;      // 50000
    const int E = in_sizes[1] / 2;        // 800000
    const int* row = ei;
    const int* col = ei + E;

    // workspace
    unsigned* zp = (unsigned*)d_ws;                       // N*256 u32
    unsigned* hp = zp + (size_t)N * ZW;                   // N*256 u32 (meta overlay)
    unsigned short* wsp = (unsigned short*)(hp + (size_t)N * ZW);  // 294912 ushorts
    int* deg  = (int*)(wsp + 294912);                     // N
    int* off  = deg + N;                                  // N+1
    int* cur  = off + N + 1;                              // N
    int* bsum = cur + N;                                  // 64
    int* btot = bsum + 64;                                // 80
    int2* meta = (int2*)hp;                               // overlays hp (disjoint lifetime)

    const int TB = 256;
    const int NB = (N + 1023) / 1024;

    prep_w_kernel<<<256, TB, 0, stream>>>(W0, W1, W2, wsp);
    init_kernel<<<2048, TB, 0, stream>>>(x, zp, deg, N);
    degree_kernel<<<1024, TB, 0, stream>>>(col, deg, E, N);
    scan_part_kernel<<<NB, 1024, 0, stream>>>(deg, off, bsum, N);
    scan_tops_kernel<<<1, 64, 0, stream>>>(bsum, btot, NB);
    scan_add_kernel<<<NB, 1024, 0, stream>>>(off, cur, btot, N, NB);
    scatter_kernel<<<1024, TB, 0, stream>>>(row, col, deg, cur, meta, E, N);

    int spmm_blocks = (N * 64 + TB - 1) / TB;
    for (int hop = 1; hop <= 3; ++hop) {
        const unsigned* zin = zp + (hop - 1) * NCH;
        unsigned* zout      = zp + hop * NCH;
        spmm_csr_kernel<<<spmm_blocks, TB, 0, stream>>>(off, meta, zin, zout, N);
    }

    int mblocks = (N + 63) / 64;                          // 782
    mlp_fused_kernel<<<mblocks, TB, 0, stream>>>(zp, wsp, b0, b1, b2, out, N);
}